// Round 15
// baseline (160.047 us; speedup 1.0000x reference)
//
#include <hip/hip_runtime.h>
#include <math.h>

#define DMODEL 1024
#define DSTATE 16
#define DCONV 4
#define DINNER 2048
#define BATCH 2
#define SEQ 1024
#define BT (BATCH*SEQ)   // 2048
#define NC 32            // scan chunks
#define LC 32            // steps per chunk (NC*LC == SEQ)

typedef unsigned short ushort_t;
typedef __attribute__((ext_vector_type(8))) short short8;
typedef __attribute__((ext_vector_type(4))) float f32x4;

__device__ __forceinline__ ushort_t f2bf(float f) {
    union { float f; unsigned int u; } v; v.f = f;
    unsigned int r = v.u + 0x7fffu + ((v.u >> 16) & 1u);
    return (ushort_t)(r >> 16);
}
__device__ __forceinline__ float bf2f(ushort_t u) {
    union { unsigned int u; float f; } v; v.u = ((unsigned int)u) << 16;
    return v.f;
}
__device__ __forceinline__ float softplusf(float x) {
    return (x > 20.f) ? x : log1pf(__expf(x));
}

#define GLOAD_LDS16(G, L) \
  __builtin_amdgcn_global_load_lds((const __attribute__((address_space(1))) void*)(G), \
                                   (__attribute__((address_space(3))) void*)(L), 16, 0, 0)

// ---------------------------------------------------------------------------
// prep: one launch for {cast x -> bf16, zero accumulators, transpose+cast w1,
// transpose+cast w2, build wT hi/lo [96][2048] for xproj}. Grid 7232 blocks.
// ---------------------------------------------------------------------------
__global__ __launch_bounds__(256) void prep_kernel(const float* __restrict__ x,
                                                   ushort_t* __restrict__ xbf,
                                                   const float* __restrict__ w1,
                                                   ushort_t* __restrict__ w1T,
                                                   const float* __restrict__ w2,
                                                   ushort_t* __restrict__ w2T,
                                                   const float* __restrict__ wx,
                                                   ushort_t* __restrict__ wT,
                                                   float* __restrict__ zacc)
{
    __shared__ float t[32][33];
    const int bid = blockIdx.x;
    const int tid = threadIdx.x;

    if (bid < 1024) {            // cast x (BT*1024 f32 -> bf16)
        size_t i = ((size_t)bid * 256 + tid) * 8;
        float4 a = *(const float4*)&x[i];
        float4 b = *(const float4*)&x[i + 4];
        uint4 p;
        p.x = (unsigned)f2bf(a.x) | ((unsigned)f2bf(a.y) << 16);
        p.y = (unsigned)f2bf(a.z) | ((unsigned)f2bf(a.w) << 16);
        p.z = (unsigned)f2bf(b.x) | ((unsigned)f2bf(b.y) << 16);
        p.w = (unsigned)f2bf(b.z) | ((unsigned)f2bf(b.w) << 16);
        *(uint4*)&xbf[i] = p;
        if (bid < 66) {          // zero B/C/dtraw accumulators (BT*33 floats)
            size_t z = ((size_t)bid * 256 + tid) * 4;
            *(float4*)&zacc[z] = make_float4(0.f, 0.f, 0.f, 0.f);
        }
        return;
    }

    if (bid >= 7168) {           // wT: x_proj_w [2048][33] -> hi/lo [96][2048]
        __shared__ ushort_t th[32][48];
        __shared__ ushort_t tl[32][48];
        const int r0 = (bid - 7168) * 32;
        for (int e = tid; e < 32 * 48; e += 256) {
            int k = e / 48, n = e % 48;
            float v = (n < 33) ? wx[(size_t)(r0 + k) * 33 + n] : 0.f;
            ushort_t hi = f2bf(v);
            th[k][n] = hi;
            tl[k][n] = f2bf(v - bf2f(hi));
        }
        __syncthreads();
        for (int e = tid; e < 48 * 32; e += 256) {
            int n = e >> 5, k = e & 31;
            wT[(size_t)n * DINNER + r0 + k]        = th[k][n];
            wT[(size_t)(48 + n) * DINNER + r0 + k] = tl[k][n];
        }
        return;
    }

    const float* in; ushort_t* out; int R, Cc, r0, c0;
    if (bid < 5120) {            // w1: [1024][4096] -> w1T [4096][1024]
        int b2 = bid - 1024;
        in = w1; out = w1T; R = DMODEL; Cc = 2 * DINNER;
        r0 = (b2 >> 7) * 32; c0 = (b2 & 127) * 32;
    } else {                     // w2: [2048][1024] -> w2T [1024][2048]
        int b3 = bid - 5120;
        in = w2; out = w2T; R = DINNER; Cc = DMODEL;
        r0 = (b3 >> 5) * 32; c0 = (b3 & 31) * 32;
    }
    {
        int lr = tid >> 3, lc4 = (tid & 7) * 4;
        float4 v = *(const float4*)&in[(size_t)(r0 + lr) * Cc + c0 + lc4];
        t[lr][lc4 + 0] = v.x; t[lr][lc4 + 1] = v.y;
        t[lr][lc4 + 2] = v.z; t[lr][lc4 + 3] = v.w;
    }
    __syncthreads();
    {
        int oc = tid >> 3, rq = (tid & 7) * 4;
        ushort4 u;
        u.x = f2bf(t[rq + 0][oc]);
        u.y = f2bf(t[rq + 1][oc]);
        u.z = f2bf(t[rq + 2][oc]);
        u.w = f2bf(t[rq + 3][oc]);
        *(ushort4*)&out[(size_t)(c0 + oc) * R + r0 + rq] = u;
    }
}

// ---------------------------------------------------------------------------
// gemm1 (in_proj) + fused depthwise conv + SiLU.
// A[BT][1024]bf16 @ w1T[4096][1024]^T, BK=64, 128x128 tile.
// x-half blocks additionally compute rows bm-16..bm-1 (extra 16-row fragment,
// staged rows 128..143) and run conv(4)+SiLU in the epilogue via LDS cbuf,
// writing bf16 xbb directly. z-half: silu -> bf16 zsil (as before).
// Batch-start tiles (bm%1024==0) zero the 16 prefix rows (causal padding).
// ---------------------------------------------------------------------------
__global__ __launch_bounds__(256) void gemm_in(const ushort_t* __restrict__ A,
                                               const ushort_t* __restrict__ Bt,
                                               const float* __restrict__ cw,
                                               const float* __restrict__ cb,
                                               ushort_t* __restrict__ xbb,
                                               ushort_t* __restrict__ zsil)
{
    constexpr int BM = 128, BN = 128, BK = 64;
    constexpr int FM = 4, FN = 4;
    const int K = DMODEL;
    __shared__ __align__(16) ushort_t Al[144 * BK];   // 18 KB (16 extra rows)
    __shared__ __align__(16) ushort_t Bl[BN * BK];    // 16 KB
    __shared__ float cbuf[144][65];                   // 36.6 KB, padded

    const int tid  = threadIdx.x;
    const int lane = tid & 63;
    const int wid  = tid >> 6;
    const int wr   = wid >> 1;
    const int wc   = wid & 1;
    const int bm   = blockIdx.y * BM;
    const int bn   = blockIdx.x * BN;
    const bool isx = (bn < DINNER);
    const bool bnd = ((bm & 1023) == 0);   // batch-start tile

    f32x4 acc[FM][FN] = {};
    f32x4 accx[FN] = {};

    for (int k0 = 0; k0 < K; k0 += BK) {
#pragma unroll
        for (int j = 0; j < 4; j++) {
            int chunk = j * 256 + tid;
            GLOAD_LDS16(&A[(size_t)(bm + (chunk >> 3)) * K + k0 + (chunk & 7) * 8],
                        &Al[(size_t)(j * 256 + wid * 64) * 8]);
        }
        if (isx && tid < 128) {            // extra rows -> staged rows 128..143
            int chunk = 1024 + tid;
            int erow  = (chunk >> 3) - 128;               // 0..15
            int arow  = bnd ? (bm + erow) : (bm - 16 + erow);  // dummy if bnd
            GLOAD_LDS16(&A[(size_t)arow * K + k0 + (chunk & 7) * 8],
                        &Al[(size_t)(1024 + wid * 64) * 8]);
        }
#pragma unroll
        for (int j = 0; j < 4; j++) {
            int chunk = j * 256 + tid;
            GLOAD_LDS16(&Bt[(size_t)(bn + (chunk >> 3)) * K + k0 + (chunk & 7) * 8],
                        &Bl[(size_t)(j * 256 + wid * 64) * 8]);
        }
        __syncthreads();

#pragma unroll
        for (int kk = 0; kk < 2; kk++) {
            short8 af[FM], bf[FN];
#pragma unroll
            for (int m = 0; m < FM; m++)
                af[m] = *(const short8*)&Al[(wr * 64 + m * 16 + (lane & 15)) * BK
                                            + (lane >> 4) * 8 + kk * 32];
#pragma unroll
            for (int n = 0; n < FN; n++)
                bf[n] = *(const short8*)&Bl[(wc * 64 + n * 16 + (lane & 15)) * BK
                                            + (lane >> 4) * 8 + kk * 32];
#pragma unroll
            for (int m = 0; m < FM; m++)
#pragma unroll
                for (int n = 0; n < FN; n++)
                    acc[m][n] = __builtin_amdgcn_mfma_f32_16x16x32_bf16(af[m], bf[n], acc[m][n], 0, 0, 0);
            if (isx && wid < 2) {          // extra fragment on waves 0 (cols 0..63) / 1 (64..127)
                short8 afx = *(const short8*)&Al[(128 + (lane & 15)) * BK
                                                 + (lane >> 4) * 8 + kk * 32];
#pragma unroll
                for (int n = 0; n < FN; n++)
                    accx[n] = __builtin_amdgcn_mfma_f32_16x16x32_bf16(afx, bf[n], accx[n], 0, 0, 0);
            }
        }
        __syncthreads();
    }

    if (isx) {
        // two column-half phases: p=0 -> cols 0..63 (wc==0 waves), p=1 -> 64..127
#pragma unroll
        for (int p = 0; p < 2; p++) {
            if (wc == p) {
#pragma unroll
                for (int m = 0; m < FM; m++)
#pragma unroll
                    for (int n = 0; n < FN; n++) {
                        int cr = 16 + wr * 64 + m * 16 + (lane >> 4) * 4;
                        int cc = n * 16 + (lane & 15);
#pragma unroll
                        for (int r = 0; r < 4; r++)
                            cbuf[cr + r][cc] = acc[m][n][r];
                    }
                if (wid == p) {            // prefix rows 0..15 (this phase's cols)
#pragma unroll
                    for (int n = 0; n < FN; n++) {
                        int cr = (lane >> 4) * 4;
                        int cc = n * 16 + (lane & 15);
#pragma unroll
                        for (int r = 0; r < 4; r++)
                            cbuf[cr + r][cc] = bnd ? 0.f : accx[n][r];
                    }
                }
            }
            __syncthreads();
            {   // conv + SiLU over 128 rows x 64 cols of this phase
                int dl   = tid & 63, tb2 = tid >> 6;
                int gcol = bn + p * 64 + dl;
                float w0 = cw[gcol * 4 + 0], w1 = cw[gcol * 4 + 1];
                float w2 = cw[gcol * 4 + 2], w3 = cw[gcol * 4 + 3];
                float bias = cb[gcol];
#pragma unroll
                for (int ii = 0; ii < 32; ii++) {
                    int tr = tb2 + 4 * ii;
                    float s = bias;
                    s = fmaf(cbuf[tr + 13][dl], w0, s);
                    s = fmaf(cbuf[tr + 14][dl], w1, s);
                    s = fmaf(cbuf[tr + 15][dl], w2, s);
                    s = fmaf(cbuf[tr + 16][dl], w3, s);
                    float sil = s / (1.f + __expf(-s));
                    xbb[(size_t)(bm + tr) * DINNER + gcol] = f2bf(sil);
                }
            }
            __syncthreads();
        }
    } else {                     // z-half: silu -> bf16
#pragma unroll
        for (int m = 0; m < FM; m++)
#pragma unroll
            for (int n = 0; n < FN; n++) {
                int row0 = bm + wr * 64 + m * 16 + (lane >> 4) * 4;
                int col  = bn - DINNER + wc * 64 + n * 16 + (lane & 15);
#pragma unroll
                for (int r = 0; r < 4; r++) {
                    float z = acc[m][n][r];
                    zsil[(size_t)(row0 + r) * DINNER + col] = f2bf(z / (1.f + __expf(-z)));
                }
            }
    }
}

// ---------------------------------------------------------------------------
// gemm2 (out_proj): C = A @ Bt^T, BK=64, 64x64 tile.
// ---------------------------------------------------------------------------
__global__ __launch_bounds__(256) void gemm_out(const ushort_t* __restrict__ A,
                                                const ushort_t* __restrict__ Bt,
                                                float* __restrict__ C)
{
    constexpr int BM = 64, BN = 64, BK = 64;
    constexpr int AL = BM * BK / (256 * 8);
    constexpr int BL = BN * BK / (256 * 8);
    constexpr int FM = BM / 32;
    constexpr int FN = BN / 32;
    const int N = DMODEL, K = DINNER;
    __shared__ __align__(16) ushort_t Al[BM * BK];
    __shared__ __align__(16) ushort_t Bl[BN * BK];

    const int tid  = threadIdx.x;
    const int lane = tid & 63;
    const int wid  = tid >> 6;
    const int wr   = wid >> 1;
    const int wc   = wid & 1;
    const int bm   = blockIdx.y * BM;
    const int bn   = blockIdx.x * BN;

    f32x4 acc[FM][FN] = {};

    for (int k0 = 0; k0 < K; k0 += BK) {
#pragma unroll
        for (int j = 0; j < AL; j++) {
            int chunk = j * 256 + tid;
            GLOAD_LDS16(&A[(size_t)(bm + (chunk >> 3)) * K + k0 + (chunk & 7) * 8],
                        &Al[(size_t)(j * 256 + wid * 64) * 8]);
        }
#pragma unroll
        for (int j = 0; j < BL; j++) {
            int chunk = j * 256 + tid;
            GLOAD_LDS16(&Bt[(size_t)(bn + (chunk >> 3)) * K + k0 + (chunk & 7) * 8],
                        &Bl[(size_t)(j * 256 + wid * 64) * 8]);
        }
        __syncthreads();

#pragma unroll
        for (int kk = 0; kk < 2; kk++) {
            short8 af[FM], bf[FN];
#pragma unroll
            for (int m = 0; m < FM; m++)
                af[m] = *(const short8*)&Al[(wr * (BM / 2) + m * 16 + (lane & 15)) * BK
                                            + (lane >> 4) * 8 + kk * 32];
#pragma unroll
            for (int n = 0; n < FN; n++)
                bf[n] = *(const short8*)&Bl[(wc * (BN / 2) + n * 16 + (lane & 15)) * BK
                                            + (lane >> 4) * 8 + kk * 32];
#pragma unroll
            for (int m = 0; m < FM; m++)
#pragma unroll
                for (int n = 0; n < FN; n++)
                    acc[m][n] = __builtin_amdgcn_mfma_f32_16x16x32_bf16(af[m], bf[n], acc[m][n], 0, 0, 0);
        }
        __syncthreads();
    }

#pragma unroll
    for (int m = 0; m < FM; m++)
#pragma unroll
        for (int n = 0; n < FN; n++) {
            int row0 = bm + wr * (BM / 2) + m * 16 + (lane >> 4) * 4;
            int col  = bn + wc * (BN / 2) + n * 16 + (lane & 15);
#pragma unroll
            for (int r = 0; r < 4; r++)
                C[(size_t)(row0 + r) * N + col] = acc[m][n][r];
        }
}

// ---------------------------------------------------------------------------
// xproj as split-K MFMA GEMM: Btb|Ctb|dtraw = xbb @ wT^T (hi+lo).
// ---------------------------------------------------------------------------
__global__ __launch_bounds__(256) void xproj_mfma(const ushort_t* __restrict__ A,
                                                  const ushort_t* __restrict__ wT,
                                                  float* __restrict__ Btb,
                                                  float* __restrict__ Ctb,
                                                  float* __restrict__ dtraw)
{
    constexpr int BK = 64;
    __shared__ __align__(16) ushort_t Al[64 * BK];    // 8 KB
    __shared__ __align__(16) ushort_t Bl[96 * BK];    // 12 KB

    const int tid  = threadIdx.x;
    const int lane = tid & 63;
    const int wid  = tid >> 6;
    const int kc   = blockIdx.x * 256;
    const int bm   = blockIdx.y * 64;

    f32x4 acc[6] = {};

    for (int ks = 0; ks < 4; ks++) {
        const int kbase = kc + ks * BK;
#pragma unroll
        for (int j = 0; j < 2; j++) {
            int chunk = j * 256 + tid;
            GLOAD_LDS16(&A[(size_t)(bm + (chunk >> 3)) * DINNER + kbase + (chunk & 7) * 8],
                        &Al[(size_t)(j * 256 + wid * 64) * 8]);
        }
#pragma unroll
        for (int j = 0; j < 3; j++) {
            int chunk = j * 256 + tid;
            GLOAD_LDS16(&wT[(size_t)(chunk >> 3) * DINNER + kbase + (chunk & 7) * 8],
                        &Bl[(size_t)(j * 256 + wid * 64) * 8]);
        }
        __syncthreads();

#pragma unroll
        for (int kk = 0; kk < 2; kk++) {
            short8 af = *(const short8*)&Al[(wid * 16 + (lane & 15)) * BK
                                            + (lane >> 4) * 8 + kk * 32];
#pragma unroll
            for (int n = 0; n < 6; n++) {
                short8 bf = *(const short8*)&Bl[(n * 16 + (lane & 15)) * BK
                                                + (lane >> 4) * 8 + kk * 32];
                acc[n] = __builtin_amdgcn_mfma_f32_16x16x32_bf16(af, bf, acc[n], 0, 0, 0);
            }
        }
        __syncthreads();
    }

    const int n   = lane & 15;
    const int row = bm + wid * 16 + (lane >> 4) * 4;
#pragma unroll
    for (int nf = 0; nf < 3; nf++) {
        f32x4 v = acc[nf] + acc[nf + 3];
        int ng = nf * 16 + n;
        if (ng < 16) {
#pragma unroll
            for (int r = 0; r < 4; r++)
                atomicAdd(&Btb[(size_t)(row + r) * 16 + ng], v[r]);
        } else if (ng < 32) {
#pragma unroll
            for (int r = 0; r < 4; r++)
                atomicAdd(&Ctb[(size_t)(row + r) * 16 + (ng - 16)], v[r]);
        } else if (ng == 32) {
#pragma unroll
            for (int r = 0; r < 4; r++)
                atomicAdd(&dtraw[row + r], v[r]);
        }
    }
}

// ---------------------------------------------------------------------------
__device__ __forceinline__ void qpowers(float q, float* a)
{
    float q2 = q * q, q4 = q2 * q2, q8 = q4 * q4;
    a[0] = q;        a[1] = q2;       a[2] = q2 * q;   a[3] = q4;
    a[4] = q4 * q;   a[5] = q4 * q2;  a[6] = q4 * a[2];a[7] = q8;
    a[8] = q8 * q;   a[9] = q8 * q2;  a[10]= q8 * a[2];a[11]= q8 * q4;
    a[12]= q8 * a[4];a[13]= q8 * a[5];a[14]= q8 * a[6];a[15]= q8 * q8;
}

__device__ __forceinline__ bool a_structure_ok(const float* A_log, int d, float As2_0)
{
    bool ok = true;
#pragma unroll
    for (int s = 1; s < 16; s++) {
        float v = -__expf(A_log[d * 16 + s]) * 1.44269504f;
        ok &= (fabsf(v - (float)(s + 1) * As2_0) <= 1e-4f * (float)(s + 1) * fabsf(As2_0));
    }
    return ok;
}

// ---------------------------------------------------------------------------
// stage helper: bf16 xbb tile [LC][256] -> f32 xs LDS
// ---------------------------------------------------------------------------
__device__ __forceinline__ void stage_xs(const ushort_t* __restrict__ xbb,
                                         float (*xs)[256],
                                         int b, int t0, int d0, int tid)
{
#pragma unroll
    for (int j = 0; j < 4; j++) {
        int e = j * 256 + tid;
        int rr = e >> 5, cc8 = (e & 31) * 8;
        short8 v = *(const short8*)&xbb[((size_t)b * SEQ + t0 + rr) * DINNER + d0 + cc8];
#pragma unroll
        for (int k = 0; k < 8; k++)
            xs[rr][cc8 + k] = bf2f((ushort_t)v[k]);
    }
}

// ---------------------------------------------------------------------------
// scan1: thread-per-d local scan over one chunk of LC=32 steps.
// ---------------------------------------------------------------------------
__global__ __launch_bounds__(256) void scan1_kernel(const ushort_t* __restrict__ xbb,
                                                    const float* __restrict__ dtraw,
                                                    const float* __restrict__ Btb,
                                                    const float* __restrict__ A_log,
                                                    const float* __restrict__ dtw,
                                                    const float* __restrict__ dtb,
                                                    float* __restrict__ Hend,
                                                    float* __restrict__ dtsum)
{
    __shared__ float raw[LC];
    __shared__ float xs[LC][256];
    __shared__ float Bs[LC][16];

    const int tid = threadIdx.x;
    const int c   = blockIdx.x;
    const int b   = blockIdx.z;
    const int d0  = blockIdx.y * 256;
    const int d   = d0 + tid;
    const int t0  = c * LC;

    if (tid < LC / 4)
        *(float4*)&raw[tid * 4] = *(const float4*)&dtraw[b * SEQ + t0 + tid * 4];
    if (tid < 128)
        *(float4*)&Bs[0][tid * 4] = *(const float4*)&Btb[((size_t)b * SEQ + t0) * 16 + tid * 4];
    stage_xs(xbb, xs, b, t0, d0, tid);

    const float wd = dtw[d], bd = dtb[d];
    const float As2_0 = -__expf(A_log[d * 16]) * 1.44269504f;
    const bool fast = a_structure_ok(A_log, d, As2_0);

    float h[16];
#pragma unroll
    for (int s = 0; s < 16; s++) h[s] = 0.f;
    float dsum = 0.f;
    __syncthreads();

    if (fast) {
#pragma unroll 2
        for (int t = 0; t < LC; t++) {
            float dt = softplusf(fmaf(raw[t], wd, bd));
            float xv = xs[t][tid];
            float Bv[16];
#pragma unroll
            for (int s4 = 0; s4 < 4; s4++)
                *(float4*)&Bv[s4 * 4] = *(const float4*)&Bs[t][s4 * 4];
            float a[16];
            qpowers(exp2f(dt * As2_0), a);
            float dtx = dt * xv;
            dsum += dt;
#pragma unroll
            for (int s = 0; s < 16; s++)
                h[s] = fmaf(a[s], h[s], Bv[s] * dtx);
        }
    } else {
        float As2[16];
#pragma unroll
        for (int s = 0; s < 16; s++)
            As2[s] = -__expf(A_log[d * 16 + s]) * 1.44269504f;
#pragma unroll 2
        for (int t = 0; t < LC; t++) {
            float dt = softplusf(fmaf(raw[t], wd, bd));
            float xv = xs[t][tid];
            float Bv[16];
#pragma unroll
            for (int s4 = 0; s4 < 4; s4++)
                *(float4*)&Bv[s4 * 4] = *(const float4*)&Bs[t][s4 * 4];
            float dtx = dt * xv;
            dsum += dt;
#pragma unroll
            for (int s = 0; s < 16; s++)
                h[s] = fmaf(exp2f(dt * As2[s]), h[s], Bv[s] * dtx);
        }
    }

    size_t hb = (((size_t)b * NC + c) * DINNER + d) * 16;
#pragma unroll
    for (int s4 = 0; s4 < 4; s4++)
        *(float4*)&Hend[hb + s4 * 4] = *(float4*)&h[s4 * 4];
    dtsum[((size_t)b * NC + c) * DINNER + d] = dsum;
}

// ---------------------------------------------------------------------------
// carry: thread per (b,d,s); walk NC chunks; Hstart[c] = running state.
// ---------------------------------------------------------------------------
__global__ __launch_bounds__(256) void carry_kernel(const float* __restrict__ Hend,
                                                    const float* __restrict__ dtsum,
                                                    const float* __restrict__ A_log,
                                                    float* __restrict__ Hstart)
{
    const int idx = blockIdx.x * 256 + threadIdx.x;   // (b,d,s)
    const int s = idx & 15;
    const int d = (idx >> 4) & (DINNER - 1);
    const int b = idx >> 15;
    const float As2 = -__expf(A_log[d * 16 + s]) * 1.44269504f;
    float hs = 0.f;
    for (int c = 0; c < NC; c++) {
        size_t off = ((size_t)b * NC + c);
        float P  = exp2f(As2 * dtsum[off * DINNER + d]);
        size_t hi = (off * DINNER + d) * 16 + s;
        float he = Hend[hi];
        Hstart[hi] = hs;
        hs = fmaf(P, hs, he);
    }
}

// ---------------------------------------------------------------------------
// scan3: thread-per-d with h_start; in-place y; gate with precomputed
// bf16 silu(z); writes bf16 ygb.
// ---------------------------------------------------------------------------
__global__ __launch_bounds__(256) void scan3_kernel(const ushort_t* __restrict__ xbb,
                                                    const float* __restrict__ dtraw,
                                                    const float* __restrict__ Btb,
                                                    const float* __restrict__ Ctb,
                                                    const float* __restrict__ A_log,
                                                    const float* __restrict__ dtw,
                                                    const float* __restrict__ dtb,
                                                    const float* __restrict__ Hstart,
                                                    const ushort_t* __restrict__ zsil,
                                                    const float* __restrict__ Dp,
                                                    ushort_t* __restrict__ ygb)
{
    __shared__ float raw[LC];
    __shared__ float xs[LC][256];
    __shared__ float Bs[LC][16];
    __shared__ float Cs[LC][16];

    const int tid = threadIdx.x;
    const int c   = blockIdx.x;
    const int b   = blockIdx.z;
    const int d0  = blockIdx.y * 256;
    const int d   = d0 + tid;
    const int t0  = c * LC;

    if (tid < LC / 4)
        *(float4*)&raw[tid * 4] = *(const float4*)&dtraw[b * SEQ + t0 + tid * 4];
    if (tid < 128)
        *(float4*)&Bs[0][tid * 4] = *(const float4*)&Btb[((size_t)b * SEQ + t0) * 16 + tid * 4];
    else {
        int u = tid - 128;
        *(float4*)&Cs[0][u * 4] = *(const float4*)&Ctb[((size_t)b * SEQ + t0) * 16 + u * 4];
    }
    stage_xs(xbb, xs, b, t0, d0, tid);

    const float wd = dtw[d], bd = dtb[d];
    const float Dd = Dp[d];
    const float As2_0 = -__expf(A_log[d * 16]) * 1.44269504f;
    const bool fast = a_structure_ok(A_log, d, As2_0);

    float h[16];
    {
        size_t hb = (((size_t)b * NC + c) * DINNER + d) * 16;
#pragma unroll
        for (int s4 = 0; s4 < 4; s4++)
            *(float4*)&h[s4 * 4] = *(const float4*)&Hstart[hb + s4 * 4];
    }
    __syncthreads();

    if (fast) {
#pragma unroll 2
        for (int t = 0; t < LC; t++) {
            float dt = softplusf(fmaf(raw[t], wd, bd));
            float xv = xs[t][tid];
            float Bv[16], Cv[16];
#pragma unroll
            for (int s4 = 0; s4 < 4; s4++) {
                *(float4*)&Bv[s4 * 4] = *(const float4*)&Bs[t][s4 * 4];
                *(float4*)&Cv[s4 * 4] = *(const float4*)&Cs[t][s4 * 4];
            }
            float a[16];
            qpowers(exp2f(dt * As2_0), a);
            float dtx = dt * xv;
            float acc = 0.f;
#pragma unroll
            for (int s = 0; s < 16; s++) {
                h[s] = fmaf(a[s], h[s], Bv[s] * dtx);
                acc = fmaf(h[s], Cv[s], acc);
            }
            xs[t][tid] = fmaf(Dd, xv, acc);
        }
    } else {
        float As2[16];
#pragma unroll
        for (int s = 0; s < 16; s++)
            As2[s] = -__expf(A_log[d * 16 + s]) * 1.44269504f;
#pragma unroll 2
        for (int t = 0; t < LC; t++) {
            float dt = softplusf(fmaf(raw[t], wd, bd));
            float xv = xs[t][tid];
            float Bv[16], Cv[16];
#pragma unroll
            for (int s4 = 0; s4 < 4; s4++) {
                *(float4*)&Bv[s4 * 4] = *(const float4*)&Bs[t][s4 * 4];
                *(float4*)&Cv[s4 * 4] = *(const float4*)&Cs[t][s4 * 4];
            }
            float dtx = dt * xv;
            float acc = 0.f;
#pragma unroll
            for (int s = 0; s < 16; s++) {
                h[s] = fmaf(exp2f(dt * As2[s]), h[s], Bv[s] * dtx);
                acc = fmaf(h[s], Cv[s], acc);
            }
            xs[t][tid] = fmaf(Dd, xv, acc);
        }
    }
    __syncthreads();

    // gate: ygb = y * silu(z) (silu precomputed bf16), coalesced
#pragma unroll
    for (int j = 0; j < 8; j++) {
        int e = j * 256 + tid;
        int rr = e >> 6, c4 = (e & 63) * 4;
        float4 yv = *(const float4*)&xs[rr][c4];
        ushort4 zv = *(const ushort4*)&zsil[((size_t)b * SEQ + t0 + rr) * DINNER + d0 + c4];
        ushort4 u;
        u.x = f2bf(yv.x * bf2f(zv.x));
        u.y = f2bf(yv.y * bf2f(zv.y));
        u.z = f2bf(yv.z * bf2f(zv.z));
        u.w = f2bf(yv.w * bf2f(zv.w));
        *(ushort4*)&ygb[((size_t)b * SEQ + t0 + rr) * DINNER + d0 + c4] = u;
    }
}

// ---------------------------------------------------------------------------
extern "C" void kernel_launch(void* const* d_in, const int* in_sizes, int n_in,
                              void* d_out, int out_size, void* d_ws, size_t ws_size,
                              hipStream_t stream)
{
    const float* x         = (const float*)d_in[0];
    const float* in_proj_w = (const float*)d_in[1];
    const float* conv_w    = (const float*)d_in[2];
    const float* conv_b    = (const float*)d_in[3];
    const float* x_proj_w  = (const float*)d_in[4];
    const float* dt_proj_w = (const float*)d_in[5];
    const float* dt_proj_b = (const float*)d_in[6];
    const float* A_log     = (const float*)d_in[7];
    const float* D_param   = (const float*)d_in[8];
    const float* c_proj_w  = (const float*)d_in[9];
    float* out = (float*)d_out;

    float* ws    = (float*)d_ws;
    float* Btb   = ws;                                   // BT*16
    float* Ctb   = Btb + (size_t)BT * 16;                // BT*16
    float* dtraw = Ctb + (size_t)BT * 16;                // BT (B,C,dt contiguous BT*33)
    float* Hend  = dtraw + BT;                           // B*NC*D*16
    float* Hstart= Hend + (size_t)BATCH * NC * DINNER * 16;
    float* dtsum = Hstart + (size_t)BATCH * NC * DINNER * 16; // B*NC*D
    ushort_t* xbf  = (ushort_t*)(dtsum + (size_t)BATCH * NC * DINNER);
    ushort_t* w1T  = xbf + (size_t)BT * DMODEL;          // 4096*1024 bf16
    ushort_t* w2T  = w1T + (size_t)(2 * DINNER) * DMODEL;// 1024*2048 bf16
    ushort_t* ygb  = w2T + (size_t)DMODEL * DINNER;      // BT*2048 bf16
    ushort_t* zsil = ygb + (size_t)BT * DINNER;          // BT*2048 bf16
    ushort_t* xbb  = zsil + (size_t)BT * DINNER;         // BT*2048 bf16 (x_branch)
    ushort_t* wT   = xbb + (size_t)BT * DINNER;          // 96*2048 bf16 (xproj hi/lo)

    // 0. prep: cast x, transpose+cast w1/w2, build wT hi/lo, zero accumulators
    prep_kernel<<<dim3(1024 + 4096 + 2048 + 64), 256, 0, stream>>>(
        x, xbf, in_proj_w, w1T, c_proj_w, w2T, x_proj_w, wT, Btb);

    // 1. in_proj GEMM + fused conv/SiLU (x-half -> xbb) and silu z-half
    gemm_in<<<dim3(32, 16), 256, 0, stream>>>(xbf, w1T, conv_w, conv_b, xbb, zsil);

    // 2. x_ssm projection: split-K MFMA GEMM with atomic epilogue
    xproj_mfma<<<dim3(8, 32), 256, 0, stream>>>(xbb, wT, Btb, Ctb, dtraw);

    // 3. chunked scan: local -> carry -> final(+fused gate, bf16 out)
    scan1_kernel<<<dim3(NC, DINNER / 256, BATCH), 256, 0, stream>>>(
        xbb, dtraw, Btb, A_log, dt_proj_w, dt_proj_b, Hend, dtsum);
    carry_kernel<<<dim3(BATCH * DINNER * 16 / 256), 256, 0, stream>>>(
        Hend, dtsum, A_log, Hstart);
    scan3_kernel<<<dim3(NC, DINNER / 256, BATCH), 256, 0, stream>>>(
        xbb, dtraw, Btb, Ctb, A_log, dt_proj_w, dt_proj_b, Hstart, zsil, D_param, ygb);

    // 4. out_proj GEMM
    gemm_out<<<dim3(16, 32), 256, 0, stream>>>(ygb, w2T, out);
}

// Round 16
// 141.619 us; speedup vs baseline: 1.1301x; 1.1301x over previous
//
#include <hip/hip_runtime.h>
#include <math.h>

#define DMODEL 1024
#define DSTATE 16
#define DCONV 4
#define DINNER 2048
#define BATCH 2
#define SEQ 1024
#define BT (BATCH*SEQ)   // 2048
#define NC 32            // scan chunks
#define LC 32            // steps per chunk (NC*LC == SEQ)

typedef unsigned short ushort_t;
typedef __attribute__((ext_vector_type(8))) short short8;
typedef __attribute__((ext_vector_type(4))) float f32x4;

__device__ __forceinline__ ushort_t f2bf(float f) {
    union { float f; unsigned int u; } v; v.f = f;
    unsigned int r = v.u + 0x7fffu + ((v.u >> 16) & 1u);
    return (ushort_t)(r >> 16);
}
__device__ __forceinline__ float bf2f(ushort_t u) {
    union { unsigned int u; float f; } v; v.u = ((unsigned int)u) << 16;
    return v.f;
}
__device__ __forceinline__ float softplusf(float x) {
    return (x > 20.f) ? x : log1pf(__expf(x));
}

#define GLOAD_LDS16(G, L) \
  __builtin_amdgcn_global_load_lds((const __attribute__((address_space(1))) void*)(G), \
                                   (__attribute__((address_space(3))) void*)(L), 16, 0, 0)

// ---------------------------------------------------------------------------
// prep: one launch for {cast x -> bf16, zero accumulators, transpose+cast w1,
// transpose+cast w2, build wT hi/lo [96][2048] for xproj}. Grid 7232 blocks.
// ---------------------------------------------------------------------------
__global__ __launch_bounds__(256) void prep_kernel(const float* __restrict__ x,
                                                   ushort_t* __restrict__ xbf,
                                                   const float* __restrict__ w1,
                                                   ushort_t* __restrict__ w1T,
                                                   const float* __restrict__ w2,
                                                   ushort_t* __restrict__ w2T,
                                                   const float* __restrict__ wx,
                                                   ushort_t* __restrict__ wT,
                                                   float* __restrict__ zacc)
{
    __shared__ float t[32][33];
    const int bid = blockIdx.x;
    const int tid = threadIdx.x;

    if (bid < 1024) {            // cast x (BT*1024 f32 -> bf16)
        size_t i = ((size_t)bid * 256 + tid) * 8;
        float4 a = *(const float4*)&x[i];
        float4 b = *(const float4*)&x[i + 4];
        uint4 p;
        p.x = (unsigned)f2bf(a.x) | ((unsigned)f2bf(a.y) << 16);
        p.y = (unsigned)f2bf(a.z) | ((unsigned)f2bf(a.w) << 16);
        p.z = (unsigned)f2bf(b.x) | ((unsigned)f2bf(b.y) << 16);
        p.w = (unsigned)f2bf(b.z) | ((unsigned)f2bf(b.w) << 16);
        *(uint4*)&xbf[i] = p;
        if (bid < 66) {          // zero B/C/dtraw accumulators (BT*33 floats)
            size_t z = ((size_t)bid * 256 + tid) * 4;
            *(float4*)&zacc[z] = make_float4(0.f, 0.f, 0.f, 0.f);
        }
        return;
    }

    if (bid >= 7168) {           // wT: x_proj_w [2048][33] -> hi/lo [96][2048]
        __shared__ ushort_t th[32][48];
        __shared__ ushort_t tl[32][48];
        const int r0 = (bid - 7168) * 32;
        for (int e = tid; e < 32 * 48; e += 256) {
            int k = e / 48, n = e % 48;
            float v = (n < 33) ? wx[(size_t)(r0 + k) * 33 + n] : 0.f;
            ushort_t hi = f2bf(v);
            th[k][n] = hi;
            tl[k][n] = f2bf(v - bf2f(hi));
        }
        __syncthreads();
        for (int e = tid; e < 48 * 32; e += 256) {
            int n = e >> 5, k = e & 31;
            wT[(size_t)n * DINNER + r0 + k]        = th[k][n];
            wT[(size_t)(48 + n) * DINNER + r0 + k] = tl[k][n];
        }
        return;
    }

    const float* in; ushort_t* out; int R, Cc, r0, c0;
    if (bid < 5120) {            // w1: [1024][4096] -> w1T [4096][1024]
        int b2 = bid - 1024;
        in = w1; out = w1T; R = DMODEL; Cc = 2 * DINNER;
        r0 = (b2 >> 7) * 32; c0 = (b2 & 127) * 32;
    } else {                     // w2: [2048][1024] -> w2T [1024][2048]
        int b3 = bid - 5120;
        in = w2; out = w2T; R = DINNER; Cc = DMODEL;
        r0 = (b3 >> 5) * 32; c0 = (b3 & 31) * 32;
    }
    {
        int lr = tid >> 3, lc4 = (tid & 7) * 4;
        float4 v = *(const float4*)&in[(size_t)(r0 + lr) * Cc + c0 + lc4];
        t[lr][lc4 + 0] = v.x; t[lr][lc4 + 1] = v.y;
        t[lr][lc4 + 2] = v.z; t[lr][lc4 + 3] = v.w;
    }
    __syncthreads();
    {
        int oc = tid >> 3, rq = (tid & 7) * 4;
        ushort4 u;
        u.x = f2bf(t[rq + 0][oc]);
        u.y = f2bf(t[rq + 1][oc]);
        u.z = f2bf(t[rq + 2][oc]);
        u.w = f2bf(t[rq + 3][oc]);
        *(ushort4*)&out[(size_t)(c0 + oc) * R + r0 + rq] = u;
    }
}

// ---------------------------------------------------------------------------
// gemm1 (in_proj): A[BT][1024]bf16 @ w1T[4096][1024]^T. BK=64, 128x128 tile.
// Epilogue: x-half -> bf16 xzb; z-half -> silu -> bf16 zsil.
// ---------------------------------------------------------------------------
__global__ __launch_bounds__(256) void gemm_in(const ushort_t* __restrict__ A,
                                               const ushort_t* __restrict__ Bt,
                                               ushort_t* __restrict__ xzb,
                                               ushort_t* __restrict__ zsil)
{
    constexpr int BM = 128, BN = 128, BK = 64;
    constexpr int AL = BM * BK / (256 * 8);
    constexpr int BL = BN * BK / (256 * 8);
    constexpr int FM = BM / 32;
    constexpr int FN = BN / 32;
    const int K = DMODEL;
    __shared__ __align__(16) ushort_t Al[BM * BK];
    __shared__ __align__(16) ushort_t Bl[BN * BK];

    const int tid  = threadIdx.x;
    const int lane = tid & 63;
    const int wid  = tid >> 6;
    const int wr   = wid >> 1;
    const int wc   = wid & 1;
    const int bm   = blockIdx.y * BM;
    const int bn   = blockIdx.x * BN;

    f32x4 acc[FM][FN] = {};

    for (int k0 = 0; k0 < K; k0 += BK) {
#pragma unroll
        for (int j = 0; j < AL; j++) {
            int chunk = j * 256 + tid;
            GLOAD_LDS16(&A[(size_t)(bm + (chunk >> 3)) * K + k0 + (chunk & 7) * 8],
                        &Al[(size_t)(j * 256 + wid * 64) * 8]);
        }
#pragma unroll
        for (int j = 0; j < BL; j++) {
            int chunk = j * 256 + tid;
            GLOAD_LDS16(&Bt[(size_t)(bn + (chunk >> 3)) * K + k0 + (chunk & 7) * 8],
                        &Bl[(size_t)(j * 256 + wid * 64) * 8]);
        }
        __syncthreads();

#pragma unroll
        for (int kk = 0; kk < 2; kk++) {
            short8 af[FM], bf[FN];
#pragma unroll
            for (int m = 0; m < FM; m++)
                af[m] = *(const short8*)&Al[(wr * (BM / 2) + m * 16 + (lane & 15)) * BK
                                            + (lane >> 4) * 8 + kk * 32];
#pragma unroll
            for (int n = 0; n < FN; n++)
                bf[n] = *(const short8*)&Bl[(wc * (BN / 2) + n * 16 + (lane & 15)) * BK
                                            + (lane >> 4) * 8 + kk * 32];
#pragma unroll
            for (int m = 0; m < FM; m++)
#pragma unroll
                for (int n = 0; n < FN; n++)
                    acc[m][n] = __builtin_amdgcn_mfma_f32_16x16x32_bf16(af[m], bf[n], acc[m][n], 0, 0, 0);
        }
        __syncthreads();
    }

    if (bn < DINNER) {           // x-half: bf16, compact stride 2048
#pragma unroll
        for (int m = 0; m < FM; m++)
#pragma unroll
            for (int n = 0; n < FN; n++) {
                int row0 = bm + wr * (BM / 2) + m * 16 + (lane >> 4) * 4;
                int col  = bn + wc * (BN / 2) + n * 16 + (lane & 15);
#pragma unroll
                for (int r = 0; r < 4; r++)
                    xzb[(size_t)(row0 + r) * DINNER + col] = f2bf(acc[m][n][r]);
            }
    } else {                     // z-half: silu -> bf16
#pragma unroll
        for (int m = 0; m < FM; m++)
#pragma unroll
            for (int n = 0; n < FN; n++) {
                int row0 = bm + wr * (BM / 2) + m * 16 + (lane >> 4) * 4;
                int col  = bn - DINNER + wc * (BN / 2) + n * 16 + (lane & 15);
#pragma unroll
                for (int r = 0; r < 4; r++) {
                    float z = acc[m][n][r];
                    zsil[(size_t)(row0 + r) * DINNER + col] = f2bf(z / (1.f + __expf(-z)));
                }
            }
    }
}

// ---------------------------------------------------------------------------
// gemm2 (out_proj): C = A @ Bt^T, BK=64, 64x64 tile.
// ---------------------------------------------------------------------------
__global__ __launch_bounds__(256) void gemm_out(const ushort_t* __restrict__ A,
                                                const ushort_t* __restrict__ Bt,
                                                float* __restrict__ C)
{
    constexpr int BM = 64, BN = 64, BK = 64;
    constexpr int AL = BM * BK / (256 * 8);
    constexpr int BL = BN * BK / (256 * 8);
    constexpr int FM = BM / 32;
    constexpr int FN = BN / 32;
    const int N = DMODEL, K = DINNER;
    __shared__ __align__(16) ushort_t Al[BM * BK];
    __shared__ __align__(16) ushort_t Bl[BN * BK];

    const int tid  = threadIdx.x;
    const int lane = tid & 63;
    const int wid  = tid >> 6;
    const int wr   = wid >> 1;
    const int wc   = wid & 1;
    const int bm   = blockIdx.y * BM;
    const int bn   = blockIdx.x * BN;

    f32x4 acc[FM][FN] = {};

    for (int k0 = 0; k0 < K; k0 += BK) {
#pragma unroll
        for (int j = 0; j < AL; j++) {
            int chunk = j * 256 + tid;
            GLOAD_LDS16(&A[(size_t)(bm + (chunk >> 3)) * K + k0 + (chunk & 7) * 8],
                        &Al[(size_t)(j * 256 + wid * 64) * 8]);
        }
#pragma unroll
        for (int j = 0; j < BL; j++) {
            int chunk = j * 256 + tid;
            GLOAD_LDS16(&Bt[(size_t)(bn + (chunk >> 3)) * K + k0 + (chunk & 7) * 8],
                        &Bl[(size_t)(j * 256 + wid * 64) * 8]);
        }
        __syncthreads();

#pragma unroll
        for (int kk = 0; kk < 2; kk++) {
            short8 af[FM], bf[FN];
#pragma unroll
            for (int m = 0; m < FM; m++)
                af[m] = *(const short8*)&Al[(wr * (BM / 2) + m * 16 + (lane & 15)) * BK
                                            + (lane >> 4) * 8 + kk * 32];
#pragma unroll
            for (int n = 0; n < FN; n++)
                bf[n] = *(const short8*)&Bl[(wc * (BN / 2) + n * 16 + (lane & 15)) * BK
                                            + (lane >> 4) * 8 + kk * 32];
#pragma unroll
            for (int m = 0; m < FM; m++)
#pragma unroll
                for (int n = 0; n < FN; n++)
                    acc[m][n] = __builtin_amdgcn_mfma_f32_16x16x32_bf16(af[m], bf[n], acc[m][n], 0, 0, 0);
        }
        __syncthreads();
    }

#pragma unroll
    for (int m = 0; m < FM; m++)
#pragma unroll
        for (int n = 0; n < FN; n++) {
            int row0 = bm + wr * (BM / 2) + m * 16 + (lane >> 4) * 4;
            int col  = bn + wc * (BN / 2) + n * 16 + (lane & 15);
#pragma unroll
            for (int r = 0; r < 4; r++)
                C[(size_t)(row0 + r) * N + col] = acc[m][n][r];
        }
}

// ---------------------------------------------------------------------------
// xproj as split-K MFMA GEMM: Btb|Ctb|dtraw = xbb @ wT^T (hi+lo).
// ---------------------------------------------------------------------------
__global__ __launch_bounds__(256) void xproj_mfma(const ushort_t* __restrict__ A,
                                                  const ushort_t* __restrict__ wT,
                                                  float* __restrict__ Btb,
                                                  float* __restrict__ Ctb,
                                                  float* __restrict__ dtraw)
{
    constexpr int BK = 64;
    __shared__ __align__(16) ushort_t Al[64 * BK];    // 8 KB
    __shared__ __align__(16) ushort_t Bl[96 * BK];    // 12 KB

    const int tid  = threadIdx.x;
    const int lane = tid & 63;
    const int wid  = tid >> 6;
    const int kc   = blockIdx.x * 256;
    const int bm   = blockIdx.y * 64;

    f32x4 acc[6] = {};

    for (int ks = 0; ks < 4; ks++) {
        const int kbase = kc + ks * BK;
#pragma unroll
        for (int j = 0; j < 2; j++) {
            int chunk = j * 256 + tid;
            GLOAD_LDS16(&A[(size_t)(bm + (chunk >> 3)) * DINNER + kbase + (chunk & 7) * 8],
                        &Al[(size_t)(j * 256 + wid * 64) * 8]);
        }
#pragma unroll
        for (int j = 0; j < 3; j++) {
            int chunk = j * 256 + tid;
            GLOAD_LDS16(&wT[(size_t)(chunk >> 3) * DINNER + kbase + (chunk & 7) * 8],
                        &Bl[(size_t)(j * 256 + wid * 64) * 8]);
        }
        __syncthreads();

#pragma unroll
        for (int kk = 0; kk < 2; kk++) {
            short8 af = *(const short8*)&Al[(wid * 16 + (lane & 15)) * BK
                                            + (lane >> 4) * 8 + kk * 32];
#pragma unroll
            for (int n = 0; n < 6; n++) {
                short8 bf = *(const short8*)&Bl[(n * 16 + (lane & 15)) * BK
                                                + (lane >> 4) * 8 + kk * 32];
                acc[n] = __builtin_amdgcn_mfma_f32_16x16x32_bf16(af, bf, acc[n], 0, 0, 0);
            }
        }
        __syncthreads();
    }

    const int n   = lane & 15;
    const int row = bm + wid * 16 + (lane >> 4) * 4;
#pragma unroll
    for (int nf = 0; nf < 3; nf++) {
        f32x4 v = acc[nf] + acc[nf + 3];
        int ng = nf * 16 + n;
        if (ng < 16) {
#pragma unroll
            for (int r = 0; r < 4; r++)
                atomicAdd(&Btb[(size_t)(row + r) * 16 + ng], v[r]);
        } else if (ng < 32) {
#pragma unroll
            for (int r = 0; r < 4; r++)
                atomicAdd(&Ctb[(size_t)(row + r) * 16 + (ng - 16)], v[r]);
        } else if (ng == 32) {
#pragma unroll
            for (int r = 0; r < 4; r++)
                atomicAdd(&dtraw[row + r], v[r]);
        }
    }
}

// ---------------------------------------------------------------------------
// Depthwise causal conv(4) + bias + SiLU. Reads bf16 xzb, writes bf16 xbb.
// ---------------------------------------------------------------------------
__global__ __launch_bounds__(256) void conv_silu_kernel(const ushort_t* __restrict__ xzb,
                                                        const float* __restrict__ cw,
                                                        const float* __restrict__ cb,
                                                        ushort_t* __restrict__ xbb)
{
    __shared__ float tile[64 + 3][64];
    const int b  = blockIdx.z;
    const int t0 = blockIdx.x * 64;
    const int d0 = blockIdx.y * 64;
    const int tid = threadIdx.x;

    for (int e = tid; e < 67 * 8; e += 256) {
        int r  = e >> 3;
        int c8 = (e & 7) * 8;
        int t  = t0 - 3 + r;
        if (t >= 0) {
            short8 v = *(const short8*)&xzb[((size_t)b * SEQ + t) * DINNER + d0 + c8];
#pragma unroll
            for (int k = 0; k < 8; k++)
                tile[r][c8 + k] = bf2f((ushort_t)v[k]);
        } else {
#pragma unroll
            for (int k = 0; k < 8; k++)
                tile[r][c8 + k] = 0.f;
        }
    }
    __syncthreads();

    const int dl = tid & 63;
    const int tb = tid >> 6;
    const int d  = d0 + dl;
    const float w0 = cw[d * 4 + 0], w1 = cw[d * 4 + 1];
    const float w2 = cw[d * 4 + 2], w3 = cw[d * 4 + 3];
    const float bias = cb[d];

#pragma unroll
    for (int ii = 0; ii < 16; ii++) {
        int tl = tb + 4 * ii;
        float s = bias;
        s = fmaf(tile[tl + 0][dl], w0, s);
        s = fmaf(tile[tl + 1][dl], w1, s);
        s = fmaf(tile[tl + 2][dl], w2, s);
        s = fmaf(tile[tl + 3][dl], w3, s);
        float sil = s / (1.f + __expf(-s));
        xbb[((size_t)b * SEQ + t0 + tl) * DINNER + d] = f2bf(sil);
    }
}

// ---------------------------------------------------------------------------
__device__ __forceinline__ void qpowers(float q, float* a)
{
    float q2 = q * q, q4 = q2 * q2, q8 = q4 * q4;
    a[0] = q;        a[1] = q2;       a[2] = q2 * q;   a[3] = q4;
    a[4] = q4 * q;   a[5] = q4 * q2;  a[6] = q4 * a[2];a[7] = q8;
    a[8] = q8 * q;   a[9] = q8 * q2;  a[10]= q8 * a[2];a[11]= q8 * q4;
    a[12]= q8 * a[4];a[13]= q8 * a[5];a[14]= q8 * a[6];a[15]= q8 * q8;
}

__device__ __forceinline__ bool a_structure_ok(const float* A_log, int d, float As2_0)
{
    bool ok = true;
#pragma unroll
    for (int s = 1; s < 16; s++) {
        float v = -__expf(A_log[d * 16 + s]) * 1.44269504f;
        ok &= (fabsf(v - (float)(s + 1) * As2_0) <= 1e-4f * (float)(s + 1) * fabsf(As2_0));
    }
    return ok;
}

// ---------------------------------------------------------------------------
// stage helper: bf16 xbb tile [LC][256] -> f32 xs LDS
// ---------------------------------------------------------------------------
__device__ __forceinline__ void stage_xs(const ushort_t* __restrict__ xbb,
                                         float (*xs)[256],
                                         int b, int t0, int d0, int tid)
{
#pragma unroll
    for (int j = 0; j < 4; j++) {
        int e = j * 256 + tid;
        int rr = e >> 5, cc8 = (e & 31) * 8;
        short8 v = *(const short8*)&xbb[((size_t)b * SEQ + t0 + rr) * DINNER + d0 + cc8];
#pragma unroll
        for (int k = 0; k < 8; k++)
            xs[rr][cc8 + k] = bf2f((ushort_t)v[k]);
    }
}

// ---------------------------------------------------------------------------
// scan1: thread-per-d local scan over one chunk of LC=32 steps.
// ---------------------------------------------------------------------------
__global__ __launch_bounds__(256) void scan1_kernel(const ushort_t* __restrict__ xbb,
                                                    const float* __restrict__ dtraw,
                                                    const float* __restrict__ Btb,
                                                    const float* __restrict__ A_log,
                                                    const float* __restrict__ dtw,
                                                    const float* __restrict__ dtb,
                                                    float* __restrict__ Hend,
                                                    float* __restrict__ dtsum)
{
    __shared__ float raw[LC];
    __shared__ float xs[LC][256];
    __shared__ float Bs[LC][16];

    const int tid = threadIdx.x;
    const int c   = blockIdx.x;
    const int b   = blockIdx.z;
    const int d0  = blockIdx.y * 256;
    const int d   = d0 + tid;
    const int t0  = c * LC;

    if (tid < LC / 4)
        *(float4*)&raw[tid * 4] = *(const float4*)&dtraw[b * SEQ + t0 + tid * 4];
    if (tid < 128)
        *(float4*)&Bs[0][tid * 4] = *(const float4*)&Btb[((size_t)b * SEQ + t0) * 16 + tid * 4];
    stage_xs(xbb, xs, b, t0, d0, tid);

    const float wd = dtw[d], bd = dtb[d];
    const float As2_0 = -__expf(A_log[d * 16]) * 1.44269504f;
    const bool fast = a_structure_ok(A_log, d, As2_0);

    float h[16];
#pragma unroll
    for (int s = 0; s < 16; s++) h[s] = 0.f;
    float dsum = 0.f;
    __syncthreads();

    if (fast) {
#pragma unroll 2
        for (int t = 0; t < LC; t++) {
            float dt = softplusf(fmaf(raw[t], wd, bd));
            float xv = xs[t][tid];
            float Bv[16];
#pragma unroll
            for (int s4 = 0; s4 < 4; s4++)
                *(float4*)&Bv[s4 * 4] = *(const float4*)&Bs[t][s4 * 4];
            float a[16];
            qpowers(exp2f(dt * As2_0), a);
            float dtx = dt * xv;
            dsum += dt;
#pragma unroll
            for (int s = 0; s < 16; s++)
                h[s] = fmaf(a[s], h[s], Bv[s] * dtx);
        }
    } else {
        float As2[16];
#pragma unroll
        for (int s = 0; s < 16; s++)
            As2[s] = -__expf(A_log[d * 16 + s]) * 1.44269504f;
#pragma unroll 2
        for (int t = 0; t < LC; t++) {
            float dt = softplusf(fmaf(raw[t], wd, bd));
            float xv = xs[t][tid];
            float Bv[16];
#pragma unroll
            for (int s4 = 0; s4 < 4; s4++)
                *(float4*)&Bv[s4 * 4] = *(const float4*)&Bs[t][s4 * 4];
            float dtx = dt * xv;
            dsum += dt;
#pragma unroll
            for (int s = 0; s < 16; s++)
                h[s] = fmaf(exp2f(dt * As2[s]), h[s], Bv[s] * dtx);
        }
    }

    size_t hb = (((size_t)b * NC + c) * DINNER + d) * 16;
#pragma unroll
    for (int s4 = 0; s4 < 4; s4++)
        *(float4*)&Hend[hb + s4 * 4] = *(float4*)&h[s4 * 4];
    dtsum[((size_t)b * NC + c) * DINNER + d] = dsum;
}

// ---------------------------------------------------------------------------
// carry: thread per (b,d,s); walk NC chunks; Hstart[c] = running state.
// ---------------------------------------------------------------------------
__global__ __launch_bounds__(256) void carry_kernel(const float* __restrict__ Hend,
                                                    const float* __restrict__ dtsum,
                                                    const float* __restrict__ A_log,
                                                    float* __restrict__ Hstart)
{
    const int idx = blockIdx.x * 256 + threadIdx.x;   // (b,d,s)
    const int s = idx & 15;
    const int d = (idx >> 4) & (DINNER - 1);
    const int b = idx >> 15;
    const float As2 = -__expf(A_log[d * 16 + s]) * 1.44269504f;
    float hs = 0.f;
    for (int c = 0; c < NC; c++) {
        size_t off = ((size_t)b * NC + c);
        float P  = exp2f(As2 * dtsum[off * DINNER + d]);
        size_t hi = (off * DINNER + d) * 16 + s;
        float he = Hend[hi];
        Hstart[hi] = hs;
        hs = fmaf(P, hs, he);
    }
}

// ---------------------------------------------------------------------------
// scan3: thread-per-d with h_start; in-place y; gate with precomputed
// bf16 silu(z); writes bf16 ygb.
// ---------------------------------------------------------------------------
__global__ __launch_bounds__(256) void scan3_kernel(const ushort_t* __restrict__ xbb,
                                                    const float* __restrict__ dtraw,
                                                    const float* __restrict__ Btb,
                                                    const float* __restrict__ Ctb,
                                                    const float* __restrict__ A_log,
                                                    const float* __restrict__ dtw,
                                                    const float* __restrict__ dtb,
                                                    const float* __restrict__ Hstart,
                                                    const ushort_t* __restrict__ zsil,
                                                    const float* __restrict__ Dp,
                                                    ushort_t* __restrict__ ygb)
{
    __shared__ float raw[LC];
    __shared__ float xs[LC][256];
    __shared__ float Bs[LC][16];
    __shared__ float Cs[LC][16];

    const int tid = threadIdx.x;
    const int c   = blockIdx.x;
    const int b   = blockIdx.z;
    const int d0  = blockIdx.y * 256;
    const int d   = d0 + tid;
    const int t0  = c * LC;

    if (tid < LC / 4)
        *(float4*)&raw[tid * 4] = *(const float4*)&dtraw[b * SEQ + t0 + tid * 4];
    if (tid < 128)
        *(float4*)&Bs[0][tid * 4] = *(const float4*)&Btb[((size_t)b * SEQ + t0) * 16 + tid * 4];
    else {
        int u = tid - 128;
        *(float4*)&Cs[0][u * 4] = *(const float4*)&Ctb[((size_t)b * SEQ + t0) * 16 + u * 4];
    }
    stage_xs(xbb, xs, b, t0, d0, tid);

    const float wd = dtw[d], bd = dtb[d];
    const float Dd = Dp[d];
    const float As2_0 = -__expf(A_log[d * 16]) * 1.44269504f;
    const bool fast = a_structure_ok(A_log, d, As2_0);

    float h[16];
    {
        size_t hb = (((size_t)b * NC + c) * DINNER + d) * 16;
#pragma unroll
        for (int s4 = 0; s4 < 4; s4++)
            *(float4*)&h[s4 * 4] = *(const float4*)&Hstart[hb + s4 * 4];
    }
    __syncthreads();

    if (fast) {
#pragma unroll 2
        for (int t = 0; t < LC; t++) {
            float dt = softplusf(fmaf(raw[t], wd, bd));
            float xv = xs[t][tid];
            float Bv[16], Cv[16];
#pragma unroll
            for (int s4 = 0; s4 < 4; s4++) {
                *(float4*)&Bv[s4 * 4] = *(const float4*)&Bs[t][s4 * 4];
                *(float4*)&Cv[s4 * 4] = *(const float4*)&Cs[t][s4 * 4];
            }
            float a[16];
            qpowers(exp2f(dt * As2_0), a);
            float dtx = dt * xv;
            float acc = 0.f;
#pragma unroll
            for (int s = 0; s < 16; s++) {
                h[s] = fmaf(a[s], h[s], Bv[s] * dtx);
                acc = fmaf(h[s], Cv[s], acc);
            }
            xs[t][tid] = fmaf(Dd, xv, acc);
        }
    } else {
        float As2[16];
#pragma unroll
        for (int s = 0; s < 16; s++)
            As2[s] = -__expf(A_log[d * 16 + s]) * 1.44269504f;
#pragma unroll 2
        for (int t = 0; t < LC; t++) {
            float dt = softplusf(fmaf(raw[t], wd, bd));
            float xv = xs[t][tid];
            float Bv[16], Cv[16];
#pragma unroll
            for (int s4 = 0; s4 < 4; s4++) {
                *(float4*)&Bv[s4 * 4] = *(const float4*)&Bs[t][s4 * 4];
                *(float4*)&Cv[s4 * 4] = *(const float4*)&Cs[t][s4 * 4];
            }
            float dtx = dt * xv;
            float acc = 0.f;
#pragma unroll
            for (int s = 0; s < 16; s++) {
                h[s] = fmaf(exp2f(dt * As2[s]), h[s], Bv[s] * dtx);
                acc = fmaf(h[s], Cv[s], acc);
            }
            xs[t][tid] = fmaf(Dd, xv, acc);
        }
    }
    __syncthreads();

    // gate: ygb = y * silu(z) (silu precomputed bf16), coalesced
#pragma unroll
    for (int j = 0; j < 8; j++) {
        int e = j * 256 + tid;
        int rr = e >> 6, c4 = (e & 63) * 4;
        float4 yv = *(const float4*)&xs[rr][c4];
        ushort4 zv = *(const ushort4*)&zsil[((size_t)b * SEQ + t0 + rr) * DINNER + d0 + c4];
        ushort4 u;
        u.x = f2bf(yv.x * bf2f(zv.x));
        u.y = f2bf(yv.y * bf2f(zv.y));
        u.z = f2bf(yv.z * bf2f(zv.z));
        u.w = f2bf(yv.w * bf2f(zv.w));
        *(ushort4*)&ygb[((size_t)b * SEQ + t0 + rr) * DINNER + d0 + c4] = u;
    }
}

// ---------------------------------------------------------------------------
extern "C" void kernel_launch(void* const* d_in, const int* in_sizes, int n_in,
                              void* d_out, int out_size, void* d_ws, size_t ws_size,
                              hipStream_t stream)
{
    const float* x         = (const float*)d_in[0];
    const float* in_proj_w = (const float*)d_in[1];
    const float* conv_w    = (const float*)d_in[2];
    const float* conv_b    = (const float*)d_in[3];
    const float* x_proj_w  = (const float*)d_in[4];
    const float* dt_proj_w = (const float*)d_in[5];
    const float* dt_proj_b = (const float*)d_in[6];
    const float* A_log     = (const float*)d_in[7];
    const float* D_param   = (const float*)d_in[8];
    const float* c_proj_w  = (const float*)d_in[9];
    float* out = (float*)d_out;

    float* ws    = (float*)d_ws;
    float* Btb   = ws;                                   // BT*16
    float* Ctb   = Btb + (size_t)BT * 16;                // BT*16
    float* dtraw = Ctb + (size_t)BT * 16;                // BT (B,C,dt contiguous BT*33)
    float* Hend  = dtraw + BT;                           // B*NC*D*16
    float* Hstart= Hend + (size_t)BATCH * NC * DINNER * 16;
    float* dtsum = Hstart + (size_t)BATCH * NC * DINNER * 16; // B*NC*D
    ushort_t* xbf  = (ushort_t*)(dtsum + (size_t)BATCH * NC * DINNER);
    ushort_t* w1T  = xbf + (size_t)BT * DMODEL;          // 4096*1024 bf16
    ushort_t* w2T  = w1T + (size_t)(2 * DINNER) * DMODEL;// 1024*2048 bf16
    ushort_t* ygb  = w2T + (size_t)DMODEL * DINNER;      // BT*2048 bf16
    ushort_t* zsil = ygb + (size_t)BT * DINNER;          // BT*2048 bf16
    ushort_t* xbb  = zsil + (size_t)BT * DINNER;         // BT*2048 bf16 (x_branch)
    ushort_t* xzb  = xbb + (size_t)BT * DINNER;          // BT*2048 bf16 (conv input)
    ushort_t* wT   = xzb + (size_t)BT * DINNER;          // 96*2048 bf16 (xproj hi/lo)

    // 0. prep: cast x, transpose+cast w1/w2, build wT hi/lo, zero accumulators
    prep_kernel<<<dim3(1024 + 4096 + 2048 + 64), 256, 0, stream>>>(
        x, xbf, in_proj_w, w1T, c_proj_w, w2T, x_proj_w, wT, Btb);

    // 1. in_proj GEMM, split epilogue (bf16 x-half, bf16 silu z-half)
    gemm_in<<<dim3(32, 16), 256, 0, stream>>>(xbf, w1T, xzb, zsil);

    // 2. conv + bias + silu -> bf16 x_branch
    conv_silu_kernel<<<dim3(SEQ / 64, DINNER / 64, BATCH), 256, 0, stream>>>(
        xzb, conv_w, conv_b, xbb);

    // 3. x_ssm projection: split-K MFMA GEMM with atomic epilogue
    xproj_mfma<<<dim3(8, 32), 256, 0, stream>>>(xbb, wT, Btb, Ctb, dtraw);

    // 4. chunked scan: local -> carry -> final(+fused gate, bf16 out)
    scan1_kernel<<<dim3(NC, DINNER / 256, BATCH), 256, 0, stream>>>(
        xbb, dtraw, Btb, A_log, dt_proj_w, dt_proj_b, Hend, dtsum);
    carry_kernel<<<dim3(BATCH * DINNER * 16 / 256), 256, 0, stream>>>(
        Hend, dtsum, A_log, Hstart);
    scan3_kernel<<<dim3(NC, DINNER / 256, BATCH), 256, 0, stream>>>(
        xbb, dtraw, Btb, Ctb, A_log, dt_proj_w, dt_proj_b, Hstart, zsil, D_param, ygb);

    // 5. out_proj GEMM
    gemm_out<<<dim3(16, 32), 256, 0, stream>>>(ygb, w2T, out);
}